// Round 2
// baseline (1851.365 us; speedup 1.0000x reference)
//
#include <hip/hip_runtime.h>
#include <hip/hip_fp16.h>
#include <math.h>

#define B_    128
#define NTOK  577
#define D_    512
#define E_    1024
#define KSEL  172
#define M_WG  (B_*NTOK)    // 73856
#define M_SEL (B_*KSEL)    // 22016

// ---------------- zero init (w_scores + bn stats) ----------------
__global__ void zero_kernel(float* __restrict__ w, float* __restrict__ stats) {
    int i = blockIdx.x * 256 + threadIdx.x;
    if (i < M_WG) w[i] = 0.f;
    if (i < 1024) stats[i] = 0.f;
}

// ---------------- weight-generator GEMM (fp32, fused relu + dot with wg_w2) ----
// h = relu(F @ W1 + b1); w_out[token] += sum_e h[e]*v[e]   (64x64 tile, K=512)
__global__ __launch_bounds__(256) void gemm_wg_kernel(
    const float* __restrict__ F, const float* __restrict__ W1,
    const float* __restrict__ b1, const float* __restrict__ v,
    float* __restrict__ w_out)
{
    __shared__ float As[16][68];
    __shared__ float Bs[16][64];
    __shared__ float red[64][17];
    const int tx = threadIdx.x, ty = threadIdx.y;
    const int tid = ty * 16 + tx;
    const int rowbase = blockIdx.y * 64;
    const int nbase = blockIdx.x * 64;
    const int lm = tid >> 4, lk = tid & 15;
    const int ln = tid & 63, lkr = tid >> 6;
    float c[4][4] = {};
    for (int k0 = 0; k0 < 512; k0 += 16) {
        for (int mm = lm; mm < 64; mm += 16)
            As[lk][mm] = F[(size_t)(rowbase + mm) * 512 + k0 + lk];
        for (int kk = lkr; kk < 16; kk += 4)
            Bs[kk][ln] = W1[(size_t)(k0 + kk) * 512 + nbase + ln];
        __syncthreads();
#pragma unroll
        for (int kk = 0; kk < 16; kk++) {
            float4 a = *(const float4*)&As[kk][ty * 4];
            float4 b = *(const float4*)&Bs[kk][tx * 4];
            float av[4] = {a.x, a.y, a.z, a.w};
            float bv[4] = {b.x, b.y, b.z, b.w};
#pragma unroll
            for (int i = 0; i < 4; i++)
#pragma unroll
                for (int j = 0; j < 4; j++)
                    c[i][j] = fmaf(av[i], bv[j], c[i][j]);
        }
        __syncthreads();
    }
    float p[4];
#pragma unroll
    for (int i = 0; i < 4; i++) {
        p[i] = 0.f;
#pragma unroll
        for (int j = 0; j < 4; j++) {
            float h = c[i][j] + b1[nbase + tx * 4 + j];
            h = fmaxf(h, 0.f);
            p[i] = fmaf(h, v[nbase + tx * 4 + j], p[i]);
        }
    }
#pragma unroll
    for (int i = 0; i < 4; i++) red[ty * 4 + i][tx] = p[i];
    __syncthreads();
    if (tid < 64) {
        float s = 0.f;
#pragma unroll
        for (int t = 0; t < 16; t++) s += red[tid][t];
        atomicAdd(&w_out[rowbase + tid], s);
    }
}

// ---------------- per-batch top-k via bitonic sort ----------------
// softmax skipped (monotone). CLS (idx 0) excluded. idx ties -> lower idx first.
__global__ __launch_bounds__(512) void topk_kernel(
    const float* __restrict__ w, int* __restrict__ idx_out)
{
    __shared__ float sval[1024];
    __shared__ int   sidx[1024];
    __shared__ int   s2[256];
    const int b = blockIdx.x;
    const int tid = threadIdx.x;
    for (int i = tid; i < 1024; i += 512) {
        if (i < 576) { sval[i] = w[b * NTOK + 1 + i]; sidx[i] = 1 + i; }
        else         { sval[i] = -1e38f;              sidx[i] = 0x7fffffff; }
    }
    __syncthreads();
    for (int ksz = 2; ksz <= 1024; ksz <<= 1) {
        for (int j = ksz >> 1; j > 0; j >>= 1) {
            int i = ((tid & ~(j - 1)) << 1) | (tid & (j - 1));
            int ixj = i | j;
            float va = sval[i], vb = sval[ixj];
            int ia = sidx[i], ib = sidx[ixj];
            bool a_first = (va > vb) || (va == vb && ia < ib); // descending
            bool dirDesc = ((i & ksz) == 0);
            bool doswap = dirDesc ? (!a_first) : a_first;
            if (doswap) { sval[i] = vb; sval[ixj] = va; sidx[i] = ib; sidx[ixj] = ia; }
            __syncthreads();
        }
    }
    // top KSEL indices -> sort ascending
    for (int i = tid; i < 256; i += 512) s2[i] = (i < KSEL) ? sidx[i] : 0x7fffffff;
    __syncthreads();
    for (int ksz = 2; ksz <= 256; ksz <<= 1) {
        for (int j = ksz >> 1; j > 0; j >>= 1) {
            if (tid < 128) {
                int i = ((tid & ~(j - 1)) << 1) | (tid & (j - 1));
                int ixj = i | j;
                int a = s2[i], bb = s2[ixj];
                bool asc = ((i & ksz) == 0);
                bool doswap = asc ? (a > bb) : (a < bb);
                if (doswap) { s2[i] = bb; s2[ixj] = a; }
            }
            __syncthreads();
        }
    }
    for (int i = tid; i < KSEL; i += 512) idx_out[b * KSEL + i] = s2[i];
}

// ---------------- gather selected tokens + l2 normalize ----------------
__global__ __launch_bounds__(128) void gather_norm_kernel(
    const float* __restrict__ F, const int* __restrict__ idx,
    float* __restrict__ sel)
{
    const int g = blockIdx.x;              // 0..M_SEL-1
    const int b = g / KSEL;
    const int tok = idx[g];
    const float4* src = (const float4*)(F + ((size_t)b * NTOK + tok) * 512);
    float4* dst = (float4*)(sel + (size_t)g * 512);
    const int t = threadIdx.x;             // 128 threads x float4 = 512
    float4 v = src[t];
    float ss = v.x * v.x + v.y * v.y + v.z * v.z + v.w * v.w;
#pragma unroll
    for (int off = 32; off > 0; off >>= 1) ss += __shfl_down(ss, off);
    __shared__ float red[2];
    if ((t & 63) == 0) red[t >> 6] = ss;
    __syncthreads();
    float inv = 1.0f / (sqrtf(red[0] + red[1]) + 1e-8f);
    float4 o; o.x = v.x * inv; o.y = v.y * inv; o.z = v.z * inv; o.w = v.w * inv;
    dst[t] = o;
}

// ---------------- fc GEMM (fp16-rounded operands, fp32 accum) -> d_out ------
__global__ __launch_bounds__(256) void gemm_fc_kernel(
    const float* __restrict__ A, const float* __restrict__ Bw,
    const float* __restrict__ bias, float* __restrict__ out)
{
    __shared__ float As[16][68];
    __shared__ float Bs[16][64];
    const int tx = threadIdx.x, ty = threadIdx.y;
    const int tid = ty * 16 + tx;
    const int rowbase = blockIdx.y * 64;
    const int nbase = blockIdx.x * 64;
    const int lm = tid >> 4, lk = tid & 15;
    const int ln = tid & 63, lkr = tid >> 6;
    float c[4][4] = {};
    for (int k0 = 0; k0 < 512; k0 += 16) {
        for (int mm = lm; mm < 64; mm += 16)
            As[lk][mm] = __half2float(__float2half(A[(size_t)(rowbase + mm) * 512 + k0 + lk]));
        for (int kk = lkr; kk < 16; kk += 4)
            Bs[kk][ln] = __half2float(__float2half(Bw[(size_t)(k0 + kk) * 1024 + nbase + ln]));
        __syncthreads();
#pragma unroll
        for (int kk = 0; kk < 16; kk++) {
            float4 a = *(const float4*)&As[kk][ty * 4];
            float4 b = *(const float4*)&Bs[kk][tx * 4];
            float av[4] = {a.x, a.y, a.z, a.w};
            float bv[4] = {b.x, b.y, b.z, b.w};
#pragma unroll
            for (int i = 0; i < 4; i++)
#pragma unroll
                for (int j = 0; j < 4; j++)
                    c[i][j] = fmaf(av[i], bv[j], c[i][j]);
        }
        __syncthreads();
    }
#pragma unroll
    for (int i = 0; i < 4; i++)
#pragma unroll
        for (int j = 0; j < 4; j++) {
            int row = rowbase + ty * 4 + i, col = nbase + tx * 4 + j;
            float r = c[i][j] + __half2float(__float2half(bias[col]));
            r = __half2float(__float2half(r));   // feats stored in fp16 by reference
            out[(size_t)row * 1024 + col] = r;
        }
}

// ---------------- mlp GEMM1: x1 = sel @ w0 + b0 ----------------
__global__ __launch_bounds__(256) void gemm_x1_kernel(
    const float* __restrict__ A, const float* __restrict__ Bw,
    const float* __restrict__ bias, float* __restrict__ X1)
{
    __shared__ float As[16][68];
    __shared__ float Bs[16][64];
    const int tx = threadIdx.x, ty = threadIdx.y;
    const int tid = ty * 16 + tx;
    const int rowbase = blockIdx.y * 64;
    const int nbase = blockIdx.x * 64;
    const int lm = tid >> 4, lk = tid & 15;
    const int ln = tid & 63, lkr = tid >> 6;
    float c[4][4] = {};
    for (int k0 = 0; k0 < 512; k0 += 16) {
        for (int mm = lm; mm < 64; mm += 16)
            As[lk][mm] = A[(size_t)(rowbase + mm) * 512 + k0 + lk];
        for (int kk = lkr; kk < 16; kk += 4)
            Bs[kk][ln] = Bw[(size_t)(k0 + kk) * 512 + nbase + ln];
        __syncthreads();
#pragma unroll
        for (int kk = 0; kk < 16; kk++) {
            float4 a = *(const float4*)&As[kk][ty * 4];
            float4 b = *(const float4*)&Bs[kk][tx * 4];
            float av[4] = {a.x, a.y, a.z, a.w};
            float bv[4] = {b.x, b.y, b.z, b.w};
#pragma unroll
            for (int i = 0; i < 4; i++)
#pragma unroll
                for (int j = 0; j < 4; j++)
                    c[i][j] = fmaf(av[i], bv[j], c[i][j]);
        }
        __syncthreads();
    }
#pragma unroll
    for (int i = 0; i < 4; i++)
#pragma unroll
        for (int j = 0; j < 4; j++) {
            int row = rowbase + ty * 4 + i, col = nbase + tx * 4 + j;
            X1[(size_t)row * 512 + col] = c[i][j] + bias[col];
        }
}

// ---------------- BN stats (sum, sumsq per column over 22016 rows) ----------
__global__ __launch_bounds__(256) void bn_stats_kernel(
    const float* __restrict__ X, float* __restrict__ stats)
{
    const int tid = threadIdx.x;
    const int c0 = tid, c1 = tid + 256;
    float s0 = 0, q0 = 0, s1 = 0, q1 = 0;
    const int r0 = blockIdx.x * (M_SEL / 128);
    for (int r = r0; r < r0 + (M_SEL / 128); r++) {
        float v0 = X[(size_t)r * 512 + c0];
        float v1 = X[(size_t)r * 512 + c1];
        s0 += v0; q0 += v0 * v0; s1 += v1; q1 += v1 * v1;
    }
    atomicAdd(&stats[c0], s0);
    atomicAdd(&stats[512 + c0], q0);
    atomicAdd(&stats[c1], s1);
    atomicAdd(&stats[512 + c1], q1);
}

__global__ void bn_finalize_kernel(const float* __restrict__ stats,
                                   const float* __restrict__ g,
                                   const float* __restrict__ b,
                                   float* __restrict__ ss)
{
    int c = threadIdx.x;  // 512
    float mean = stats[c] * (1.0f / M_SEL);
    float var = stats[512 + c] * (1.0f / M_SEL) - mean * mean;
    float sc = g[c] * rsqrtf(var + 1e-5f);
    ss[c] = sc;
    ss[512 + c] = b[c] - mean * sc;
}

// ---------------- mlp GEMM2 with fused BN+ReLU on A-load; out += ------------
__global__ __launch_bounds__(256) void gemm_out_kernel(
    const float* __restrict__ X, const float* __restrict__ Bw,
    const float* __restrict__ bias, const float* __restrict__ ss,
    float* __restrict__ out)
{
    __shared__ float As[16][68];
    __shared__ float Bs[16][64];
    __shared__ float sscale[512], sshift[512];
    const int tx = threadIdx.x, ty = threadIdx.y;
    const int tid = ty * 16 + tx;
    const int rowbase = blockIdx.y * 64;
    const int nbase = blockIdx.x * 64;
    const int lm = tid >> 4, lk = tid & 15;
    const int ln = tid & 63, lkr = tid >> 6;
    for (int c0 = tid; c0 < 512; c0 += 256) {
        sscale[c0] = ss[c0];
        sshift[c0] = ss[512 + c0];
    }
    __syncthreads();
    float c[4][4] = {};
    for (int k0 = 0; k0 < 512; k0 += 16) {
        for (int mm = lm; mm < 64; mm += 16) {
            float v = X[(size_t)(rowbase + mm) * 512 + k0 + lk];
            As[lk][mm] = fmaxf(fmaf(v, sscale[k0 + lk], sshift[k0 + lk]), 0.f);
        }
        for (int kk = lkr; kk < 16; kk += 4)
            Bs[kk][ln] = Bw[(size_t)(k0 + kk) * 1024 + nbase + ln];
        __syncthreads();
#pragma unroll
        for (int kk = 0; kk < 16; kk++) {
            float4 a = *(const float4*)&As[kk][ty * 4];
            float4 b = *(const float4*)&Bs[kk][tx * 4];
            float av[4] = {a.x, a.y, a.z, a.w};
            float bv[4] = {b.x, b.y, b.z, b.w};
#pragma unroll
            for (int i = 0; i < 4; i++)
#pragma unroll
                for (int j = 0; j < 4; j++)
                    c[i][j] = fmaf(av[i], bv[j], c[i][j]);
        }
        __syncthreads();
    }
#pragma unroll
    for (int i = 0; i < 4; i++)
#pragma unroll
        for (int j = 0; j < 4; j++) {
            int row = rowbase + ty * 4 + i, col = nbase + tx * 4 + j;
            size_t o = (size_t)row * 1024 + col;
            out[o] = out[o] + c[i][j] + bias[col];
        }
}

extern "C" void kernel_launch(void* const* d_in, const int* in_sizes, int n_in,
                              void* d_out, int out_size, void* d_ws, size_t ws_size,
                              hipStream_t stream)
{
    const float* features = (const float*)d_in[0];
    // d_in[1] atten: unused by reference
    const float* wg_w1 = (const float*)d_in[2];
    const float* wg_b1 = (const float*)d_in[3];
    const float* wg_w2 = (const float*)d_in[4];
    // d_in[5] wg_b2: constant shift, irrelevant for top-k ranking
    const float* fc_w  = (const float*)d_in[6];
    const float* fc_b  = (const float*)d_in[7];
    const float* mlp_w0 = (const float*)d_in[8];
    const float* mlp_b0 = (const float*)d_in[9];
    const float* bn_g  = (const float*)d_in[10];
    const float* bn_b  = (const float*)d_in[11];
    const float* mlp_w1 = (const float*)d_in[12];
    const float* mlp_b1 = (const float*)d_in[13];
    float* out = (float*)d_out;

    char* ws = (char*)d_ws;
    float* w_scores  = (float*)(ws + 0);          // 73856 f32
    float* stats     = (float*)(ws + 295424);     // 1024 f32 (sum, sumsq)
    float* scaleshift= (float*)(ws + 299520);     // 1024 f32 (scale, shift)
    int*   idx_sel   = (int*)  (ws + 303616);     // 22016 i32
    float* sel       = (float*)(ws + 391680);     // 22016*512 f32 (45.1 MB)
    float* x1        = (float*)(ws + 45480448);   // 22016*512 f32 (45.1 MB)
    // total ws use: ~90.6 MB

    zero_kernel<<<289, 256, 0, stream>>>(w_scores, stats);
    gemm_wg_kernel<<<dim3(8, 1154), dim3(16, 16), 0, stream>>>(
        features, wg_w1, wg_b1, wg_w2, w_scores);
    topk_kernel<<<B_, 512, 0, stream>>>(w_scores, idx_sel);
    gather_norm_kernel<<<M_SEL, 128, 0, stream>>>(features, idx_sel, sel);
    gemm_fc_kernel<<<dim3(16, 344), dim3(16, 16), 0, stream>>>(sel, fc_w, fc_b, out);
    gemm_x1_kernel<<<dim3(8, 344), dim3(16, 16), 0, stream>>>(sel, mlp_w0, mlp_b0, x1);
    bn_stats_kernel<<<128, 256, 0, stream>>>(x1, stats);
    bn_finalize_kernel<<<1, 512, 0, stream>>>(stats, bn_g, bn_b, scaleshift);
    gemm_out_kernel<<<dim3(16, 344), dim3(16, 16), 0, stream>>>(
        x1, mlp_w1, mlp_b1, scaleshift, out);
}

// Round 3
// 624.272 us; speedup vs baseline: 2.9656x; 2.9656x over previous
//
#include <hip/hip_runtime.h>
#include <hip/hip_fp16.h>
#include <math.h>

#define B_    128
#define NTOK  577
#define D_    512
#define E_    1024
#define KSEL  172
#define M_WG  (B_*NTOK)    // 73856 = 577*128
#define M_SEL (B_*KSEL)    // 22016 = 172*128

typedef float f32x4 __attribute__((ext_vector_type(4)));
typedef short s16x8 __attribute__((ext_vector_type(8)));
typedef short s16x4 __attribute__((ext_vector_type(4)));

__device__ __forceinline__ unsigned short bf16_rne(float x) {
    unsigned u = __float_as_uint(x);
    u += 0x7FFFu + ((u >> 16) & 1u);
    return (unsigned short)(u >> 16);
}
__device__ __forceinline__ float bf16f(unsigned short h) {
    return __uint_as_float(((unsigned)h) << 16);
}

// ---------------- zero init (w_scores + bn stats) ----------------
__global__ void zero_kernel(float* __restrict__ w, float* __restrict__ stats) {
    int i = blockIdx.x * 256 + threadIdx.x;
    if (i < M_WG) w[i] = 0.f;
    if (i < 1024) stats[i] = 0.f;
}

// ---------------- weight transpose + bf16 hi/lo split (runs once per call) ---
// W[k][n] f32 -> Wt_h[n][k], Wt_l[n][k] bf16 (k-contiguous rows for MFMA B-frags)
__global__ __launch_bounds__(256) void transpose_split_kernel(
    const float* __restrict__ wgw1, const float* __restrict__ mw0,
    const float* __restrict__ mw1, const float* __restrict__ fcw,
    short* __restrict__ w1t_h, short* __restrict__ w1t_l,
    short* __restrict__ w0t_h, short* __restrict__ w0t_l,
    short* __restrict__ mw1t_h, short* __restrict__ mw1t_l,
    short* __restrict__ fct_h, short* __restrict__ fct_l)
{
    const int z = blockIdx.z;
    const float* src; short *dh, *dl; int N; bool f16r = false;
    if (z == 0)      { src = wgw1; dh = w1t_h;  dl = w1t_l;  N = 512; }
    else if (z == 1) { src = mw0;  dh = w0t_h;  dl = w0t_l;  N = 512; }
    else if (z == 2) { src = mw1;  dh = mw1t_h; dl = mw1t_l; N = 1024; }
    else             { src = fcw;  dh = fct_h;  dl = fct_l;  N = 1024; f16r = true; }
    const int n0 = blockIdx.x * 64;
    if (n0 >= N) return;
    const int k0 = blockIdx.y * 64;
    __shared__ float t[64][65];
    const int tid = threadIdx.x;
#pragma unroll
    for (int rr = 0; rr < 16; rr++) {
        int kl = rr * 4 + (tid >> 6);
        int nl = tid & 63;
        t[kl][nl] = src[(size_t)(k0 + kl) * N + n0 + nl];
    }
    __syncthreads();
    const int nl = tid >> 2, kc = tid & 3;
    short hs[16], ls[16];
#pragma unroll
    for (int j = 0; j < 16; j++) {
        float x = t[kc * 16 + j][nl];
        if (f16r) x = __half2float(__float2half(x));
        unsigned short h = bf16_rne(x);
        hs[j] = (short)h;
        ls[j] = (short)bf16_rne(x - bf16f(h));
    }
    size_t o = (size_t)(n0 + nl) * 512 + k0 + kc * 16;
    *(s16x8*)(dh + o)     = *(s16x8*)hs;
    *(s16x8*)(dh + o + 8) = *(s16x8*)(hs + 8);
    *(s16x8*)(dl + o)     = *(s16x8*)ls;
    *(s16x8*)(dl + o + 8) = *(s16x8*)(ls + 8);
}

// ---------------- shared GEMM building blocks ----------------
// stage pre-split bf16 [rows][Ktot] -> LDS [128][32] (k-contiguous)
__device__ __forceinline__ void stage_bf16(short* dst, const short* __restrict__ src,
                                           int row_base, int k0, int Ktot, int tid)
{
#pragma unroll
    for (int p = 0; p < 2; p++) {
        int c = tid + p * 256;
        int n = c >> 2, kc = c & 3;
        s16x8 v = *(const s16x8*)(src + (size_t)(row_base + n) * Ktot + k0 + kc * 8);
        *(s16x8*)(dst + c * 8) = v;
    }
}

// load f32 [rows][Ktot], optional BN-affine+relu, split into hi/lo bf16 LDS tiles
template<bool AFFINE>
__device__ __forceinline__ void stage_f32_split(short* dstH, short* dstL,
    const float* __restrict__ src, int row_base, int k0, int Ktot, int tid,
    const float* sc, const float* sh)
{
#pragma unroll
    for (int p = 0; p < 2; p++) {
        int c = tid + p * 256;
        int n = c >> 2, kc = c & 3;
        const float* s = src + (size_t)(row_base + n) * Ktot + k0 + kc * 8;
        float4 v0 = *(const float4*)(s);
        float4 v1 = *(const float4*)(s + 4);
        float vv[8] = {v0.x, v0.y, v0.z, v0.w, v1.x, v1.y, v1.z, v1.w};
        short hs[8], ls[8];
#pragma unroll
        for (int j = 0; j < 8; j++) {
            float x = vv[j];
            if (AFFINE) {
                int k = k0 + kc * 8 + j;
                x = fmaxf(fmaf(x, sc[k], sh[k]), 0.f);
            }
            unsigned short h = bf16_rne(x);
            hs[j] = (short)h;
            ls[j] = (short)bf16_rne(x - bf16f(h));
        }
        *(s16x8*)(dstH + c * 8) = *(s16x8*)hs;
        *(s16x8*)(dstL + c * 8) = *(s16x8*)ls;
    }
}

// bf16x2-split MFMA on a 128x128x32 tile: acc += Ah*Bh + Ah*Bl + Al*Bh
__device__ __forceinline__ void mfma_x2_tile(
    const short* Ah, const short* Al, const short* Bh, const short* Bl,
    f32x4 acc[4][4], int wm, int wn, int lane)
{
    const int r = lane & 15, kq = lane >> 4;
    s16x8 ah[4], al[4], bh[4], bl[4];
#pragma unroll
    for (int mf = 0; mf < 4; mf++) {
        int off = (wm * 64 + mf * 16 + r) * 32 + kq * 8;
        ah[mf] = *(const s16x8*)(Ah + off);
        al[mf] = *(const s16x8*)(Al + off);
    }
#pragma unroll
    for (int nf = 0; nf < 4; nf++) {
        int off = (wn * 64 + nf * 16 + r) * 32 + kq * 8;
        bh[nf] = *(const s16x8*)(Bh + off);
        bl[nf] = *(const s16x8*)(Bl + off);
    }
#pragma unroll
    for (int mf = 0; mf < 4; mf++)
#pragma unroll
        for (int nf = 0; nf < 4; nf++) {
            acc[mf][nf] = __builtin_amdgcn_mfma_f32_16x16x32_bf16(ah[mf], bh[nf], acc[mf][nf], 0, 0, 0);
            acc[mf][nf] = __builtin_amdgcn_mfma_f32_16x16x32_bf16(ah[mf], bl[nf], acc[mf][nf], 0, 0, 0);
            acc[mf][nf] = __builtin_amdgcn_mfma_f32_16x16x32_bf16(al[mf], bh[nf], acc[mf][nf], 0, 0, 0);
        }
}

// ---------------- wg GEMM: scores = rowsum(relu(F@W1 + b1) * v) ----------------
__global__ __launch_bounds__(256) void gemm_wg_kernel(
    const float* __restrict__ F, const short* __restrict__ Wh, const short* __restrict__ Wl,
    const float* __restrict__ b1, const float* __restrict__ v, float* __restrict__ w_out)
{
    __shared__ short Ah[128 * 32], Al[128 * 32], Bh[128 * 32], Bl[128 * 32];
    const int tid = threadIdx.x, lane = tid & 63, w = tid >> 6;
    const int wm = w >> 1, wn = w & 1;
    const int rowbase = blockIdx.y * 128, nbase = blockIdx.x * 128;
    f32x4 acc[4][4];
#pragma unroll
    for (int i = 0; i < 4; i++)
#pragma unroll
        for (int j = 0; j < 4; j++) acc[i][j] = (f32x4)(0.0f);
    for (int k0 = 0; k0 < 512; k0 += 32) {
        stage_f32_split<false>(Ah, Al, F, rowbase, k0, 512, tid, nullptr, nullptr);
        stage_bf16(Bh, Wh, nbase, k0, 512, tid);
        stage_bf16(Bl, Wl, nbase, k0, 512, tid);
        __syncthreads();
        mfma_x2_tile(Ah, Al, Bh, Bl, acc, wm, wn, lane);
        __syncthreads();
    }
    const int r = lane & 15, kq = lane >> 4;
    float b1v[4], vv[4];
#pragma unroll
    for (int nf = 0; nf < 4; nf++) {
        int col = nbase + wn * 64 + nf * 16 + r;
        b1v[nf] = b1[col]; vv[nf] = v[col];
    }
#pragma unroll
    for (int mf = 0; mf < 4; mf++)
#pragma unroll
        for (int i = 0; i < 4; i++) {
            float s = 0.f;
#pragma unroll
            for (int nf = 0; nf < 4; nf++)
                s += fmaxf(acc[mf][nf][i] + b1v[nf], 0.f) * vv[nf];
            s += __shfl_xor(s, 1); s += __shfl_xor(s, 2);
            s += __shfl_xor(s, 4); s += __shfl_xor(s, 8);
            if (r == 0)
                atomicAdd(&w_out[rowbase + wm * 64 + mf * 16 + kq * 4 + i], s);
        }
}

// ---------------- per-batch top-k via bitonic sort (unchanged, verified) ------
__global__ __launch_bounds__(512) void topk_kernel(
    const float* __restrict__ w, int* __restrict__ idx_out)
{
    __shared__ float sval[1024];
    __shared__ int   sidx[1024];
    __shared__ int   s2[256];
    const int b = blockIdx.x;
    const int tid = threadIdx.x;
    for (int i = tid; i < 1024; i += 512) {
        if (i < 576) { sval[i] = w[b * NTOK + 1 + i]; sidx[i] = 1 + i; }
        else         { sval[i] = -1e38f;              sidx[i] = 0x7fffffff; }
    }
    __syncthreads();
    for (int ksz = 2; ksz <= 1024; ksz <<= 1) {
        for (int j = ksz >> 1; j > 0; j >>= 1) {
            int i = ((tid & ~(j - 1)) << 1) | (tid & (j - 1));
            int ixj = i | j;
            float va = sval[i], vb = sval[ixj];
            int ia = sidx[i], ib = sidx[ixj];
            bool a_first = (va > vb) || (va == vb && ia < ib);
            bool dirDesc = ((i & ksz) == 0);
            bool doswap = dirDesc ? (!a_first) : a_first;
            if (doswap) { sval[i] = vb; sval[ixj] = va; sidx[i] = ib; sidx[ixj] = ia; }
            __syncthreads();
        }
    }
    for (int i = tid; i < 256; i += 512) s2[i] = (i < KSEL) ? sidx[i] : 0x7fffffff;
    __syncthreads();
    for (int ksz = 2; ksz <= 256; ksz <<= 1) {
        for (int j = ksz >> 1; j > 0; j >>= 1) {
            if (tid < 128) {
                int i = ((tid & ~(j - 1)) << 1) | (tid & (j - 1));
                int ixj = i | j;
                int a = s2[i], bb = s2[ixj];
                bool asc = ((i & ksz) == 0);
                bool doswap = asc ? (a > bb) : (a < bb);
                if (doswap) { s2[i] = bb; s2[ixj] = a; }
            }
            __syncthreads();
        }
    }
    for (int i = tid; i < KSEL; i += 512) idx_out[b * KSEL + i] = s2[i];
}

// ------- gather + l2norm + f16-round + bf16 hi/lo split (feeds fc AND mlp0) ---
__global__ __launch_bounds__(128) void gather_norm_kernel(
    const float* __restrict__ F, const int* __restrict__ idx,
    short* __restrict__ Sh, short* __restrict__ Sl)
{
    const int g = blockIdx.x;
    const int b = g / KSEL;
    const int tok = idx[g];
    const float4* src = (const float4*)(F + ((size_t)b * NTOK + tok) * 512);
    const int t = threadIdx.x;
    float4 v = src[t];
    float ss = v.x * v.x + v.y * v.y + v.z * v.z + v.w * v.w;
#pragma unroll
    for (int off = 32; off > 0; off >>= 1) ss += __shfl_down(ss, off);
    __shared__ float red[2];
    if ((t & 63) == 0) red[t >> 6] = ss;
    __syncthreads();
    float inv = 1.0f / (sqrtf(red[0] + red[1]) + 1e-8f);
    float xs[4] = {v.x * inv, v.y * inv, v.z * inv, v.w * inv};
    short hs[4], ls[4];
#pragma unroll
    for (int j = 0; j < 4; j++) {
        float x = __half2float(__float2half(xs[j]));   // match reference .half()
        unsigned short h = bf16_rne(x);
        hs[j] = (short)h;
        ls[j] = (short)bf16_rne(x - bf16f(h));
    }
    *(s16x4*)(Sh + (size_t)g * 512 + t * 4) = *(s16x4*)hs;
    *(s16x4*)(Sl + (size_t)g * 512 + t * 4) = *(s16x4*)ls;
}

// ---------------- x1 = sel @ w0 + b0, fused BN-stats partials ----------------
__global__ __launch_bounds__(256) void gemm_x1_kernel(
    const short* __restrict__ Sh, const short* __restrict__ Sl,
    const short* __restrict__ Wh, const short* __restrict__ Wl,
    const float* __restrict__ b0, float* __restrict__ X1, float* __restrict__ stats)
{
    __shared__ short Ah[128 * 32], Al[128 * 32], Bh[128 * 32], Bl[128 * 32];
    const int tid = threadIdx.x, lane = tid & 63, w = tid >> 6;
    const int wm = w >> 1, wn = w & 1;
    const int rowbase = blockIdx.y * 128, nbase = blockIdx.x * 128;
    f32x4 acc[4][4];
#pragma unroll
    for (int i = 0; i < 4; i++)
#pragma unroll
        for (int j = 0; j < 4; j++) acc[i][j] = (f32x4)(0.0f);
    for (int k0 = 0; k0 < 512; k0 += 32) {
        stage_bf16(Ah, Sh, rowbase, k0, 512, tid);
        stage_bf16(Al, Sl, rowbase, k0, 512, tid);
        stage_bf16(Bh, Wh, nbase, k0, 512, tid);
        stage_bf16(Bl, Wl, nbase, k0, 512, tid);
        __syncthreads();
        mfma_x2_tile(Ah, Al, Bh, Bl, acc, wm, wn, lane);
        __syncthreads();
    }
    const int r = lane & 15, kq = lane >> 4;
#pragma unroll
    for (int nf = 0; nf < 4; nf++) {
        int col = nbase + wn * 64 + nf * 16 + r;
        float b0v = b0[col];
        float cs = 0.f, cq = 0.f;
#pragma unroll
        for (int mf = 0; mf < 4; mf++)
#pragma unroll
            for (int i = 0; i < 4; i++) {
                int row = rowbase + wm * 64 + mf * 16 + kq * 4 + i;
                float val = acc[mf][nf][i] + b0v;
                X1[(size_t)row * 512 + col] = val;
                cs += val; cq += val * val;
            }
        cs += __shfl_xor(cs, 16); cs += __shfl_xor(cs, 32);
        cq += __shfl_xor(cq, 16); cq += __shfl_xor(cq, 32);
        if (kq == 0) {
            atomicAdd(&stats[col], cs);
            atomicAdd(&stats[512 + col], cq);
        }
    }
}

__global__ void bn_finalize_kernel(const float* __restrict__ stats,
                                   const float* __restrict__ g,
                                   const float* __restrict__ b,
                                   float* __restrict__ ss)
{
    int c = threadIdx.x;  // 512
    float mean = stats[c] * (1.0f / M_SEL);
    float var = stats[512 + c] * (1.0f / M_SEL) - mean * mean;
    float sc = g[c] * rsqrtf(var + 1e-5f);
    ss[c] = sc;
    ss[512 + c] = b[c] - mean * sc;
}

// ---- merged: out = f16(sel@fc_w + fc_b) + (bnrelu(x1) @ w1 + b1), one write ----
__global__ __launch_bounds__(256) void gemm_out2_kernel(
    const short* __restrict__ Sh, const short* __restrict__ Sl,
    const short* __restrict__ FCh, const short* __restrict__ FCl,
    const float* __restrict__ fcb, const float* __restrict__ X1,
    const short* __restrict__ W1h, const short* __restrict__ W1l,
    const float* __restrict__ ssbuf, const float* __restrict__ b1,
    float* __restrict__ out)
{
    __shared__ short Ah[128 * 32], Al[128 * 32], Bh[128 * 32], Bl[128 * 32];
    __shared__ float sc[512], sh_[512];
    const int tid = threadIdx.x, lane = tid & 63, w = tid >> 6;
    const int wm = w >> 1, wn = w & 1;
    const int rowbase = blockIdx.y * 128, nbase = blockIdx.x * 128;
    for (int i = tid; i < 512; i += 256) { sc[i] = ssbuf[i]; sh_[i] = ssbuf[512 + i]; }
    f32x4 acc[4][4];
#pragma unroll
    for (int i = 0; i < 4; i++)
#pragma unroll
        for (int j = 0; j < 4; j++) acc[i][j] = (f32x4)(0.0f);
    // phase A: fc (f16-faithful operands, pre-split)
    for (int k0 = 0; k0 < 512; k0 += 32) {
        stage_bf16(Ah, Sh, rowbase, k0, 512, tid);
        stage_bf16(Al, Sl, rowbase, k0, 512, tid);
        stage_bf16(Bh, FCh, nbase, k0, 512, tid);
        stage_bf16(Bl, FCl, nbase, k0, 512, tid);
        __syncthreads();
        mfma_x2_tile(Ah, Al, Bh, Bl, acc, wm, wn, lane);
        __syncthreads();
    }
    // round fc partial to f16 (reference stores feats as fp16), keep in regs
    const int r = lane & 15;
#pragma unroll
    for (int nf = 0; nf < 4; nf++) {
        float fb = __half2float(__float2half(fcb[nbase + wn * 64 + nf * 16 + r]));
#pragma unroll
        for (int mf = 0; mf < 4; mf++)
#pragma unroll
            for (int i = 0; i < 4; i++) {
                float t = __half2float(__float2half(acc[mf][nf][i]));
                acc[mf][nf][i] = __half2float(__float2half(t + fb));
            }
    }
    // phase B: mlp second GEMM, BN+ReLU fused into A staging
    for (int k0 = 0; k0 < 512; k0 += 32) {
        stage_f32_split<true>(Ah, Al, X1, rowbase, k0, 512, tid, sc, sh_);
        stage_bf16(Bh, W1h, nbase, k0, 512, tid);
        stage_bf16(Bl, W1l, nbase, k0, 512, tid);
        __syncthreads();
        mfma_x2_tile(Ah, Al, Bh, Bl, acc, wm, wn, lane);
        __syncthreads();
    }
    const int kq = lane >> 4;
#pragma unroll
    for (int nf = 0; nf < 4; nf++) {
        int col = nbase + wn * 64 + nf * 16 + r;
        float bb = b1[col];
#pragma unroll
        for (int mf = 0; mf < 4; mf++)
#pragma unroll
            for (int i = 0; i < 4; i++) {
                int row = rowbase + wm * 64 + mf * 16 + kq * 4 + i;
                out[(size_t)row * 1024 + col] = acc[mf][nf][i] + bb;
            }
    }
}

extern "C" void kernel_launch(void* const* d_in, const int* in_sizes, int n_in,
                              void* d_out, int out_size, void* d_ws, size_t ws_size,
                              hipStream_t stream)
{
    const float* features = (const float*)d_in[0];
    const float* wg_w1 = (const float*)d_in[2];
    const float* wg_b1 = (const float*)d_in[3];
    const float* wg_w2 = (const float*)d_in[4];
    const float* fc_w  = (const float*)d_in[6];
    const float* fc_b  = (const float*)d_in[7];
    const float* mlp_w0 = (const float*)d_in[8];
    const float* mlp_b0 = (const float*)d_in[9];
    const float* bn_g  = (const float*)d_in[10];
    const float* bn_b  = (const float*)d_in[11];
    const float* mlp_w1 = (const float*)d_in[12];
    const float* mlp_b1 = (const float*)d_in[13];
    float* out = (float*)d_out;

    char* ws = (char*)d_ws;
    float* w_scores  = (float*)(ws + 0);          // 73856 f32
    float* stats     = (float*)(ws + 295424);     // 1024 f32
    float* scaleshift= (float*)(ws + 299520);     // 1024 f32
    int*   idx_sel   = (int*)  (ws + 303616);     // 22016 i32
    short* w1t_h     = (short*)(ws + 391680);     // wg_w1^T hi  [512][512]
    short* w1t_l     = (short*)(ws + 915968);
    short* w0t_h     = (short*)(ws + 1440256);    // mlp_w0^T    [512][512]
    short* w0t_l     = (short*)(ws + 1964544);
    short* mw1t_h    = (short*)(ws + 2488832);    // mlp_w1^T    [1024][512]
    short* mw1t_l    = (short*)(ws + 3537408);
    short* fct_h     = (short*)(ws + 4585984);    // fc_w^T (f16-rounded) [1024][512]
    short* fct_l     = (short*)(ws + 5634560);
    short* sel_h     = (short*)(ws + 6683136);    // sel f16-rounded split [22016][512]
    short* sel_l     = (short*)(ws + 29227520);
    float* x1        = (float*)(ws + 51771904);   // [22016][512] f32
    // total ws use ≈ 96.9 MB

    zero_kernel<<<289, 256, 0, stream>>>(w_scores, stats);
    transpose_split_kernel<<<dim3(16, 8, 4), 256, 0, stream>>>(
        wg_w1, mlp_w0, mlp_w1, fc_w,
        w1t_h, w1t_l, w0t_h, w0t_l, mw1t_h, mw1t_l, fct_h, fct_l);
    gemm_wg_kernel<<<dim3(4, 577), 256, 0, stream>>>(
        features, w1t_h, w1t_l, wg_b1, wg_w2, w_scores);
    topk_kernel<<<B_, 512, 0, stream>>>(w_scores, idx_sel);
    gather_norm_kernel<<<M_SEL, 128, 0, stream>>>(features, idx_sel, sel_h, sel_l);
    gemm_x1_kernel<<<dim3(4, 172), 256, 0, stream>>>(
        sel_h, sel_l, w0t_h, w0t_l, mlp_b0, x1, stats);
    bn_finalize_kernel<<<1, 512, 0, stream>>>(stats, bn_g, bn_b, scaleshift);
    gemm_out2_kernel<<<dim3(8, 172), 256, 0, stream>>>(
        sel_h, sel_l, fct_h, fct_l, fc_b, x1, mw1t_h, mw1t_l, scaleshift, mlp_b1, out);
}